// Round 1
// baseline (394.080 us; speedup 1.0000x reference)
//
#include <hip/hip_runtime.h>
#include <math.h>

#define N_CELLS 4096
#define M_GENES 8192

// per-row additive terms: a_u1[4096], a_v1[8192], a_u2[4096], a_v2[8192]
__device__ __align__(16) float g_a[24576];

// ---------------------------------------------------------------------------
// embed_u: e[row, d] = sum_k u[row,k] * Wb[k,d]   (K<=128, D=128)
// ---------------------------------------------------------------------------
__global__ __launch_bounds__(128) void embed_u_kernel(const float* __restrict__ u,
                                                      const float* __restrict__ Wb,
                                                      float* __restrict__ e,
                                                      int K)
{
    __shared__ float sU[128];
    const int row = blockIdx.x;
    const int d = threadIdx.x;
    if (d < K) sU[d] = u[row * K + d];
    __syncthreads();
    float acc = 0.f;
    for (int k = 0; k < K; ++k) acc = fmaf(sU[k], Wb[k * 128 + d], acc);
    e[row * 128 + d] = acc;
}

// ---------------------------------------------------------------------------
// rowdot: g_a[ofs + row] = sum_d E[row,d] * w[d]
// ---------------------------------------------------------------------------
__global__ __launch_bounds__(128) void rowdot_kernel(const float* __restrict__ E,
                                                     const float* __restrict__ w,
                                                     int ofs)
{
    const int row = blockIdx.x;
    const int d = threadIdx.x;
    float v = E[row * 128 + d] * w[d];
#pragma unroll
    for (int off = 32; off > 0; off >>= 1) v += __shfl_down(v, off, 64);
    __shared__ float s2[2];
    if ((d & 63) == 0) s2[d >> 6] = v;
    __syncthreads();
    if (d == 0) g_a[ofs + row] = s2[0] + s2[1];
}

// ---------------------------------------------------------------------------
// tile_nn: C[rows, Nc] = (relu?)(A[rows, K] @ B[K, Nc])
// 64x64 tile / block, 256 threads, 4x4 micro-tile, K-chunks of 32.
// ---------------------------------------------------------------------------
template<bool RELU>
__global__ __launch_bounds__(256) void tile_nn(const float* __restrict__ A,
                                               const float* __restrict__ B,
                                               float* __restrict__ C,
                                               int K, int Nc)
{
    __shared__ float sAt[32][68];   // transposed A chunk: sAt[kk][row]
    __shared__ float sB[32][68];    // B chunk: sB[kk][col]
    const int tx = threadIdx.x & 15, ty = threadIdx.x >> 4;
    const int row0 = blockIdx.y * 64, col0 = blockIdx.x * 64;
    float acc[4][4] = {};
    for (int k0 = 0; k0 < K; k0 += 32) {
#pragma unroll
        for (int rep = 0; rep < 2; ++rep) {
            const int f = threadIdx.x + rep * 256;     // 0..511
            const int r = f >> 3;                      // 0..63
            const int kc = (f & 7) << 2;               // 0,4,...,28
            const float4 av = *reinterpret_cast<const float4*>(&A[(row0 + r) * K + k0 + kc]);
            sAt[kc + 0][r] = av.x; sAt[kc + 1][r] = av.y;
            sAt[kc + 2][r] = av.z; sAt[kc + 3][r] = av.w;
            const int kk = f >> 4;                     // 0..31
            const int c4 = (f & 15) << 2;              // 0,4,...,60
            const float4 bv = *reinterpret_cast<const float4*>(&B[(k0 + kk) * Nc + col0 + c4]);
            *reinterpret_cast<float4*>(&sB[kk][c4]) = bv;
        }
        __syncthreads();
#pragma unroll
        for (int kk = 0; kk < 32; ++kk) {
            const float4 a4 = *reinterpret_cast<const float4*>(&sAt[kk][ty * 4]);
            const float4 b4 = *reinterpret_cast<const float4*>(&sB[kk][tx * 4]);
            const float ar[4] = {a4.x, a4.y, a4.z, a4.w};
            const float br[4] = {b4.x, b4.y, b4.z, b4.w};
#pragma unroll
            for (int i = 0; i < 4; ++i)
#pragma unroll
                for (int j = 0; j < 4; ++j)
                    acc[i][j] = fmaf(ar[i], br[j], acc[i][j]);
        }
        __syncthreads();
    }
#pragma unroll
    for (int i = 0; i < 4; ++i) {
        float4 o;
        o.x = acc[i][0]; o.y = acc[i][1]; o.z = acc[i][2]; o.w = acc[i][3];
        if (RELU) {
            o.x = fmaxf(o.x, 0.f); o.y = fmaxf(o.y, 0.f);
            o.z = fmaxf(o.z, 0.f); o.w = fmaxf(o.w, 0.f);
        }
        *reinterpret_cast<float4*>(&C[(row0 + ty * 4 + i) * Nc + col0 + tx * 4]) = o;
    }
}

// ---------------------------------------------------------------------------
// pair_kernel: out[n,m] = act( sum_d EU[n,d]*w_prod[d]*EV[m,d]
//                              + a_u[n] + a_v[m] + bias )
// ACT: 0 = relu, 1 = sigmoid. 64x64 tile, K=128.
// ---------------------------------------------------------------------------
template<int ACT>
__global__ __launch_bounds__(256) void pair_kernel(const float* __restrict__ EU,
                                                   const float* __restrict__ EV,
                                                   const float* __restrict__ w_prod,
                                                   const float* __restrict__ bias_p,
                                                   float* __restrict__ outp,
                                                   int ofsU, int ofsV)
{
    __shared__ float sU[32][68];
    __shared__ float sV[32][68];
    const int tx = threadIdx.x & 15, ty = threadIdx.x >> 4;
    const int row0 = blockIdx.y * 64, col0 = blockIdx.x * 64;
    float acc[4][4] = {};
    for (int k0 = 0; k0 < 128; k0 += 32) {
#pragma unroll
        for (int rep = 0; rep < 2; ++rep) {
            const int f = threadIdx.x + rep * 256;
            const int r = f >> 3;
            const int kc = (f & 7) << 2;
            const float4 wv = *reinterpret_cast<const float4*>(&w_prod[k0 + kc]);
            const float4 av = *reinterpret_cast<const float4*>(&EU[(row0 + r) * 128 + k0 + kc]);
            sU[kc + 0][r] = av.x * wv.x; sU[kc + 1][r] = av.y * wv.y;
            sU[kc + 2][r] = av.z * wv.z; sU[kc + 3][r] = av.w * wv.w;
            const float4 bv = *reinterpret_cast<const float4*>(&EV[(col0 + r) * 128 + k0 + kc]);
            sV[kc + 0][r] = bv.x; sV[kc + 1][r] = bv.y;
            sV[kc + 2][r] = bv.z; sV[kc + 3][r] = bv.w;
        }
        __syncthreads();
#pragma unroll
        for (int kk = 0; kk < 32; ++kk) {
            const float4 a4 = *reinterpret_cast<const float4*>(&sU[kk][ty * 4]);
            const float4 b4 = *reinterpret_cast<const float4*>(&sV[kk][tx * 4]);
            const float ar[4] = {a4.x, a4.y, a4.z, a4.w};
            const float br[4] = {b4.x, b4.y, b4.z, b4.w};
#pragma unroll
            for (int i = 0; i < 4; ++i)
#pragma unroll
                for (int j = 0; j < 4; ++j)
                    acc[i][j] = fmaf(ar[i], br[j], acc[i][j]);
        }
        __syncthreads();
    }
    float au[4];
#pragma unroll
    for (int i = 0; i < 4; ++i) au[i] = g_a[ofsU + row0 + ty * 4 + i];
    const float4 av4 = *reinterpret_cast<const float4*>(&g_a[ofsV + col0 + tx * 4]);
    const float avj[4] = {av4.x, av4.y, av4.z, av4.w};
    const float bias = *bias_p;
#pragma unroll
    for (int i = 0; i < 4; ++i) {
        float o[4];
#pragma unroll
        for (int j = 0; j < 4; ++j) {
            float x = acc[i][j] + au[i] + avj[j] + bias;
            if (ACT == 0) x = fmaxf(x, 0.f);
            else          x = 1.f / (1.f + expf(-x));
            o[j] = x;
        }
        const float4 ov = {o[0], o[1], o[2], o[3]};
        *reinterpret_cast<float4*>(&outp[(row0 + ty * 4 + i) * M_GENES + col0 + tx * 4]) = ov;
    }
}

// ---------------------------------------------------------------------------
extern "C" void kernel_launch(void* const* d_in, const int* in_sizes, int n_in,
                              void* d_out, int out_size, void* d_ws, size_t ws_size,
                              hipStream_t stream)
{
    const float* u1       = (const float*)d_in[0];   // [4096,100]
    const float* u2       = (const float*)d_in[1];   // [4096,100]
    const float* v1       = (const float*)d_in[2];   // [8192,256]
    const float* v2       = (const float*)d_in[3];   // [8192,512]
    const float* Wb1      = (const float*)d_in[4];   // [100,128]
    const float* Wb2      = (const float*)d_in[5];   // [100,128]
    const float* Wrna1    = (const float*)d_in[6];   // [256,256]
    const float* Wrna2    = (const float*)d_in[7];   // [256,128]
    const float* gene_act = (const float*)d_in[8];   // [512,256]
    const float* w_prod1  = (const float*)d_in[9];   // [128]
    const float* w_add1   = (const float*)d_in[10];  // [256]
    const float* w_prod2  = (const float*)d_in[11];  // [128]
    const float* w_add2   = (const float*)d_in[12];  // [256]
    const float* bias1    = (const float*)d_in[13];  // scalar
    const float* bias2    = (const float*)d_in[14];  // scalar

    float* out  = (float*)d_out;
    float* out1 = out;                                      // [4096,8192]
    float* out2 = out1 + (size_t)N_CELLS * M_GENES;         // [4096,8192]
    float* eu1  = out2 + (size_t)N_CELLS * M_GENES;         // [4096,128]
    float* ev1  = eu1 + N_CELLS * 128;                      // [8192,128]
    float* eu2  = ev1 + M_GENES * 128;                      // [4096,128]
    float* ev2  = eu2 + N_CELLS * 128;                      // [8192,128]

    // hidden-activation scratch lives in the out2 region (out2 is written
    // last, by pair_kernel<1>, after all scratch consumers are done)
    float* Ha = out2;                  // [8192,256]
    float* Hb = out2 + 8192 * 256;     // [8192,256]

    // u embeddings
    embed_u_kernel<<<N_CELLS, 128, 0, stream>>>(u1, Wb1, eu1, 100);
    embed_u_kernel<<<N_CELLS, 128, 0, stream>>>(u2, Wb2, eu2, 100);

    // v embeddings (stream 1): ev1 = relu(v1 @ Wrna1) @ Wrna2
    tile_nn<true ><<<dim3(4, 128), 256, 0, stream>>>(v1, Wrna1, Ha, 256, 256);
    tile_nn<false><<<dim3(2, 128), 256, 0, stream>>>(Ha, Wrna2, ev1, 256, 128);

    // v embeddings (stream 2): ev2 = relu((v2 @ gene_act) @ Wrna1) @ Wrna2
    tile_nn<false><<<dim3(4, 128), 256, 0, stream>>>(v2, gene_act, Hb, 512, 256);
    tile_nn<true ><<<dim3(4, 128), 256, 0, stream>>>(Hb, Wrna1, Ha, 256, 256);
    tile_nn<false><<<dim3(2, 128), 256, 0, stream>>>(Ha, Wrna2, ev2, 256, 128);

    // per-row additive terms
    rowdot_kernel<<<N_CELLS, 128, 0, stream>>>(eu1, w_add1,       0);
    rowdot_kernel<<<M_GENES, 128, 0, stream>>>(ev1, w_add1 + 128, 4096);
    rowdot_kernel<<<N_CELLS, 128, 0, stream>>>(eu2, w_add2,       12288);
    rowdot_kernel<<<M_GENES, 128, 0, stream>>>(ev2, w_add2 + 128, 16384);

    // all-pairs scores
    pair_kernel<0><<<dim3(128, 64), 256, 0, stream>>>(eu1, ev1, w_prod1, bias1, out1, 0,     4096);
    pair_kernel<1><<<dim3(128, 64), 256, 0, stream>>>(eu2, ev2, w_prod2, bias2, out2, 12288, 16384);
}

// Round 2
// 203.708 us; speedup vs baseline: 1.9345x; 1.9345x over previous
//
#include <hip/hip_runtime.h>
#include <math.h>

#define N_CELLS 4096
#define M_GENES 8192

typedef __attribute__((ext_vector_type(8))) short short8;
typedef __attribute__((ext_vector_type(4))) float f32x4;

// per-row additive terms: a_u1[4096], a_v1[8192], a_u2[4096], a_v2[8192]
__device__ __align__(16) float g_a[24576];

// bf16 copies of embeddings for the MFMA pair kernels (plain row-major [rows][128])
__device__ __align__(16) short g_bu1[N_CELLS * 128];
__device__ __align__(16) short g_bv1[M_GENES * 128];
__device__ __align__(16) short g_bu2[N_CELLS * 128];
__device__ __align__(16) short g_bv2[M_GENES * 128];

__device__ __forceinline__ short* bf_sel(int s) {
    switch (s) {
        case 0:  return g_bu1;
        case 1:  return g_bv1;
        case 2:  return g_bu2;
        default: return g_bv2;
    }
}

__device__ __forceinline__ short f2bf(float f) {  // RNE fp32 -> bf16
    unsigned u = __builtin_bit_cast(unsigned, f);
    u += 0x7FFFu + ((u >> 16) & 1u);
    return (short)(u >> 16);
}

// ---------------------------------------------------------------------------
// embed_u: e[row, d] = sum_k u[row,k] * Wb[k,d]   (K<=128, D=128)
// ---------------------------------------------------------------------------
__global__ __launch_bounds__(128) void embed_u_kernel(const float* __restrict__ u,
                                                      const float* __restrict__ Wb,
                                                      float* __restrict__ e,
                                                      int K)
{
    __shared__ float sU[128];
    const int row = blockIdx.x;
    const int d = threadIdx.x;
    if (d < K) sU[d] = u[row * K + d];
    __syncthreads();
    float acc = 0.f;
    for (int k = 0; k < K; ++k) acc = fmaf(sU[k], Wb[k * 128 + d], acc);
    e[row * 128 + d] = acc;
}

// ---------------------------------------------------------------------------
// rowdot: g_a[ofs + row] = sum_d E[row,d] * w[d]
// ---------------------------------------------------------------------------
__global__ __launch_bounds__(128) void rowdot_kernel(const float* __restrict__ E,
                                                     const float* __restrict__ w,
                                                     int ofs)
{
    const int row = blockIdx.x;
    const int d = threadIdx.x;
    float v = E[row * 128 + d] * w[d];
#pragma unroll
    for (int off = 32; off > 0; off >>= 1) v += __shfl_down(v, off, 64);
    __shared__ float s2[2];
    if ((d & 63) == 0) s2[d >> 6] = v;
    __syncthreads();
    if (d == 0) g_a[ofs + row] = s2[0] + s2[1];
}

// ---------------------------------------------------------------------------
// tile_nn: C[rows, Nc] = (relu?)(A[rows, K] @ B[K, Nc])   (fp32, exact path)
// ---------------------------------------------------------------------------
template<bool RELU>
__global__ __launch_bounds__(256) void tile_nn(const float* __restrict__ A,
                                               const float* __restrict__ B,
                                               float* __restrict__ C,
                                               int K, int Nc)
{
    __shared__ float sAt[32][68];
    __shared__ float sB[32][68];
    const int tx = threadIdx.x & 15, ty = threadIdx.x >> 4;
    const int row0 = blockIdx.y * 64, col0 = blockIdx.x * 64;
    float acc[4][4] = {};
    for (int k0 = 0; k0 < K; k0 += 32) {
#pragma unroll
        for (int rep = 0; rep < 2; ++rep) {
            const int f = threadIdx.x + rep * 256;
            const int r = f >> 3;
            const int kc = (f & 7) << 2;
            const float4 av = *reinterpret_cast<const float4*>(&A[(row0 + r) * K + k0 + kc]);
            sAt[kc + 0][r] = av.x; sAt[kc + 1][r] = av.y;
            sAt[kc + 2][r] = av.z; sAt[kc + 3][r] = av.w;
            const int kk = f >> 4;
            const int c4 = (f & 15) << 2;
            const float4 bv = *reinterpret_cast<const float4*>(&B[(k0 + kk) * Nc + col0 + c4]);
            *reinterpret_cast<float4*>(&sB[kk][c4]) = bv;
        }
        __syncthreads();
#pragma unroll
        for (int kk = 0; kk < 32; ++kk) {
            const float4 a4 = *reinterpret_cast<const float4*>(&sAt[kk][ty * 4]);
            const float4 b4 = *reinterpret_cast<const float4*>(&sB[kk][tx * 4]);
            const float ar[4] = {a4.x, a4.y, a4.z, a4.w};
            const float br[4] = {b4.x, b4.y, b4.z, b4.w};
#pragma unroll
            for (int i = 0; i < 4; ++i)
#pragma unroll
                for (int j = 0; j < 4; ++j)
                    acc[i][j] = fmaf(ar[i], br[j], acc[i][j]);
        }
        __syncthreads();
    }
#pragma unroll
    for (int i = 0; i < 4; ++i) {
        float4 o;
        o.x = acc[i][0]; o.y = acc[i][1]; o.z = acc[i][2]; o.w = acc[i][3];
        if (RELU) {
            o.x = fmaxf(o.x, 0.f); o.y = fmaxf(o.y, 0.f);
            o.z = fmaxf(o.z, 0.f); o.w = fmaxf(o.w, 0.f);
        }
        *reinterpret_cast<float4*>(&C[(row0 + ty * 4 + i) * Nc + col0 + tx * 4]) = o;
    }
}

// ---------------------------------------------------------------------------
// cvt_bf16: bf16 copy of an embedding array, optionally folding w_prod.
// Each thread handles one 16-byte (8-element) chunk.
// ---------------------------------------------------------------------------
template<bool SCALE>
__global__ __launch_bounds__(256) void cvt_bf16(const float* __restrict__ in,
                                                const float* __restrict__ w,
                                                int sel)
{
    const int c = blockIdx.x * 256 + threadIdx.x;     // chunk id
    const float4* p = reinterpret_cast<const float4*>(in) + (size_t)c * 2;
    float4 x0 = p[0], x1 = p[1];
    if (SCALE) {
        const int k = (c * 8) & 127;
        const float4 w0 = *reinterpret_cast<const float4*>(w + k);
        const float4 w1 = *reinterpret_cast<const float4*>(w + k + 4);
        x0.x *= w0.x; x0.y *= w0.y; x0.z *= w0.z; x0.w *= w0.w;
        x1.x *= w1.x; x1.y *= w1.y; x1.z *= w1.z; x1.w *= w1.w;
    }
    short8 o;
    o[0] = f2bf(x0.x); o[1] = f2bf(x0.y); o[2] = f2bf(x0.z); o[3] = f2bf(x0.w);
    o[4] = f2bf(x1.x); o[5] = f2bf(x1.y); o[6] = f2bf(x1.z); o[7] = f2bf(x1.w);
    *reinterpret_cast<short8*>(bf_sel(sel) + (size_t)c * 8) = o;
}

// ---------------------------------------------------------------------------
// pair_mfma: out[n,m] = act( sum_d EU'[n,d]*EV[m,d] + a_u[n] + a_v[m] + bias )
// bf16 MFMA 16x16x32; 128x128 output tile; K=128 staged once in LDS.
// LDS rows XOR-swizzled (byte ^= (row&7)<<4) -> uniform bank load on
// ds_read_b128 (would be 32-way conflict unswizzled, guide §6 G4).
// ACT: 0 = relu, 1 = sigmoid.
// ---------------------------------------------------------------------------
template<int ACT>
__global__ __launch_bounds__(256) void pair_mfma(int which,
                                                 const float* __restrict__ bias_p,
                                                 float* __restrict__ outp,
                                                 int ofsU, int ofsV)
{
    __shared__ __align__(16) short sA[128 * 128];
    __shared__ __align__(16) short sB[128 * 128];
    const int t = threadIdx.x;
    const int l = t & 63;
    const int row0 = blockIdx.y * 128;   // EU rows
    const int col0 = blockIdx.x * 128;   // EV rows (output cols)

    // ---- stage both tiles (contiguous 32 KB each), swizzled on ds_write ----
    {
        const short8* gA = reinterpret_cast<const short8*>(bf_sel(which ? 2 : 0)) + (size_t)row0 * 16;
        const short8* gB = reinterpret_cast<const short8*>(bf_sel(which ? 3 : 1)) + (size_t)col0 * 16;
        char* cA = (char*)sA;
        char* cB = (char*)sB;
#pragma unroll
        for (int c = 0; c < 8; ++c) {
            const int idx = c * 256 + t;                 // 16B chunk, 0..2047
            const int row = idx >> 4;
            const int sub = idx & 15;
            const int dst = row * 256 + ((sub * 16) ^ ((row & 7) << 4));
            const short8 va = gA[idx];
            const short8 vb = gB[idx];
            *reinterpret_cast<short8*>(cA + dst) = va;
            *reinterpret_cast<short8*>(cB + dst) = vb;
        }
    }
    __syncthreads();

    // ---- MFMA: wave (2x2) x fragment (4x4) over the 128x128 tile ----
    const int w  = t >> 6;
    const int wm = (w >> 1) * 64;
    const int wn = (w & 1) * 64;
    const int lr = l & 15;            // fragment row (A) / col (B) lane
    const int lkb = (l >> 4) * 16;    // k sub-offset in bytes

    f32x4 acc[4][4] = {};
    const char* cA = (const char*)sA;
    const char* cB = (const char*)sB;
#pragma unroll
    for (int kk = 0; kk < 4; ++kk) {
        const int kb = kk * 64 + lkb;         // byte offset of k within row
        short8 a[4], b[4];
#pragma unroll
        for (int i = 0; i < 4; ++i) {
            const int rowA = wm + i * 16 + lr;
            a[i] = *reinterpret_cast<const short8*>(cA + rowA * 256 + (kb ^ ((rowA & 7) << 4)));
            const int rowB = wn + i * 16 + lr;
            b[i] = *reinterpret_cast<const short8*>(cB + rowB * 256 + (kb ^ ((rowB & 7) << 4)));
        }
#pragma unroll
        for (int i = 0; i < 4; ++i)
#pragma unroll
            for (int j = 0; j < 4; ++j)
                acc[i][j] = __builtin_amdgcn_mfma_f32_16x16x32_bf16(a[i], b[j], acc[i][j], 0, 0, 0);
    }

    // ---- epilogue: additive terms + bias + activation ----
    const float bias = *bias_p;
    const int r4 = (l >> 4) * 4;
    float au[4][4];
#pragma unroll
    for (int i = 0; i < 4; ++i)
#pragma unroll
        for (int r = 0; r < 4; ++r)
            au[i][r] = g_a[ofsU + row0 + wm + i * 16 + r4 + r];
    float av[4];
#pragma unroll
    for (int j = 0; j < 4; ++j)
        av[j] = g_a[ofsV + col0 + wn + j * 16 + lr];

#pragma unroll
    for (int i = 0; i < 4; ++i) {
#pragma unroll
        for (int r = 0; r < 4; ++r) {
            const int grow = row0 + wm + i * 16 + r4 + r;
            float* orow = outp + (size_t)grow * M_GENES + col0 + wn;
#pragma unroll
            for (int j = 0; j < 4; ++j) {
                float x = acc[i][j][r] + au[i][r] + av[j] + bias;
                if (ACT == 0) x = fmaxf(x, 0.f);
                else          x = __builtin_amdgcn_rcpf(1.f + __expf(-x));
                orow[j * 16 + lr] = x;
            }
        }
    }
}

// ---------------------------------------------------------------------------
extern "C" void kernel_launch(void* const* d_in, const int* in_sizes, int n_in,
                              void* d_out, int out_size, void* d_ws, size_t ws_size,
                              hipStream_t stream)
{
    const float* u1       = (const float*)d_in[0];   // [4096,100]
    const float* u2       = (const float*)d_in[1];   // [4096,100]
    const float* v1       = (const float*)d_in[2];   // [8192,256]
    const float* v2       = (const float*)d_in[3];   // [8192,512]
    const float* Wb1      = (const float*)d_in[4];   // [100,128]
    const float* Wb2      = (const float*)d_in[5];   // [100,128]
    const float* Wrna1    = (const float*)d_in[6];   // [256,256]
    const float* Wrna2    = (const float*)d_in[7];   // [256,128]
    const float* gene_act = (const float*)d_in[8];   // [512,256]
    const float* w_prod1  = (const float*)d_in[9];   // [128]
    const float* w_add1   = (const float*)d_in[10];  // [256]
    const float* w_prod2  = (const float*)d_in[11];  // [128]
    const float* w_add2   = (const float*)d_in[12];  // [256]
    const float* bias1    = (const float*)d_in[13];  // scalar
    const float* bias2    = (const float*)d_in[14];  // scalar

    float* out  = (float*)d_out;
    float* out1 = out;                                      // [4096,8192]
    float* out2 = out1 + (size_t)N_CELLS * M_GENES;         // [4096,8192]
    float* eu1  = out2 + (size_t)N_CELLS * M_GENES;         // [4096,128]
    float* ev1  = eu1 + N_CELLS * 128;                      // [8192,128]
    float* eu2  = ev1 + M_GENES * 128;                      // [4096,128]
    float* ev2  = eu2 + N_CELLS * 128;                      // [8192,128]

    // hidden-activation scratch lives in the out2 region (out2 is written
    // last, by pair_mfma<1>, after all scratch consumers are done)
    float* Ha = out2;                  // [8192,256]
    float* Hb = out2 + 8192 * 256;     // [8192,256]

    // u embeddings (exact fp32 path — these are checked outputs)
    embed_u_kernel<<<N_CELLS, 128, 0, stream>>>(u1, Wb1, eu1, 100);
    embed_u_kernel<<<N_CELLS, 128, 0, stream>>>(u2, Wb2, eu2, 100);

    // v embeddings (exact fp32 path)
    tile_nn<true ><<<dim3(4, 128), 256, 0, stream>>>(v1, Wrna1, Ha, 256, 256);
    tile_nn<false><<<dim3(2, 128), 256, 0, stream>>>(Ha, Wrna2, ev1, 256, 128);
    tile_nn<false><<<dim3(4, 128), 256, 0, stream>>>(v2, gene_act, Hb, 512, 256);
    tile_nn<true ><<<dim3(4, 128), 256, 0, stream>>>(Hb, Wrna1, Ha, 256, 256);
    tile_nn<false><<<dim3(2, 128), 256, 0, stream>>>(Ha, Wrna2, ev2, 256, 128);

    // per-row additive terms
    rowdot_kernel<<<N_CELLS, 128, 0, stream>>>(eu1, w_add1,       0);
    rowdot_kernel<<<M_GENES, 128, 0, stream>>>(ev1, w_add1 + 128, 4096);
    rowdot_kernel<<<N_CELLS, 128, 0, stream>>>(eu2, w_add2,       12288);
    rowdot_kernel<<<M_GENES, 128, 0, stream>>>(ev2, w_add2 + 128, 16384);

    // bf16 copies for the pair MFMA (w_prod folded into EU before rounding)
    cvt_bf16<true ><<<N_CELLS * 16 / 256, 256, 0, stream>>>(eu1, w_prod1, 0);
    cvt_bf16<false><<<M_GENES * 16 / 256, 256, 0, stream>>>(ev1, nullptr, 1);
    cvt_bf16<true ><<<N_CELLS * 16 / 256, 256, 0, stream>>>(eu2, w_prod2, 2);
    cvt_bf16<false><<<M_GENES * 16 / 256, 256, 0, stream>>>(ev2, nullptr, 3);

    // all-pairs scores via bf16 MFMA
    pair_mfma<0><<<dim3(64, 32), 256, 0, stream>>>(0, bias1, out1, 0,     4096);
    pair_mfma<1><<<dim3(64, 32), 256, 0, stream>>>(1, bias2, out2, 12288, 16384);
}

// Round 5
// 138.013 us; speedup vs baseline: 2.8554x; 1.4760x over previous
//
#include <hip/hip_runtime.h>
#include <math.h>

#define N_CELLS 4096
#define M_GENES 8192

typedef __attribute__((ext_vector_type(8))) short short8;
typedef __attribute__((ext_vector_type(4))) float f32x4;

// per-row additive terms: a_u1[4096], a_v1[8192], a_u2[4096], a_v2[8192]
__device__ __align__(16) float g_a[24576];

// bf16 copies feeding pair MFMA (g_bu: w_prod folded; g_bv: plain)
__device__ __align__(16) short g_bu1[N_CELLS * 128];
__device__ __align__(16) short g_bv1[M_GENES * 128];
__device__ __align__(16) short g_bu2[N_CELLS * 128];
__device__ __align__(16) short g_bv2[M_GENES * 128];

// transposed bf16 weights: BT[ncol][k]  (small -> keep as globals)
__device__ __align__(16) short g_gaT[256 * 512];       // gene_act^T
__device__ __align__(16) short g_W1T[256 * 256];       // Wrna1^T
__device__ __align__(16) short g_W2T[128 * 256];       // Wrna2^T

// IMPORTANT: device globals are NEVER passed as kernel arguments from host
// code (the host-side name is the shadow symbol, not the device address —
// that was the round-3/4 abort). All global access goes through these
// device-side selectors, with only small ints crossing the ABI.

__device__ __forceinline__ short* bf_sel(int s) {
    switch (s) {
        case 0:  return g_bu1;
        case 1:  return g_bv1;
        case 2:  return g_bu2;
        default: return g_bv2;
    }
}

__device__ __forceinline__ const short* wt_sel(int s) {
    switch (s) {
        case 0:  return g_gaT;
        case 1:  return g_W1T;
        default: return g_W2T;
    }
}

__device__ __forceinline__ short f2bf(float f) {  // RNE fp32 -> bf16
    unsigned u = __builtin_bit_cast(unsigned, f);
    u += 0x7FFFu + ((u >> 16) & 1u);
    return (short)(u >> 16);
}

__device__ __forceinline__ void cvt8(const float* __restrict__ in, short* __restrict__ out) {
    const float4 x0 = *reinterpret_cast<const float4*>(in);
    const float4 x1 = *reinterpret_cast<const float4*>(in + 4);
    short8 o;
    o[0] = f2bf(x0.x); o[1] = f2bf(x0.y); o[2] = f2bf(x0.z); o[3] = f2bf(x0.w);
    o[4] = f2bf(x1.x); o[5] = f2bf(x1.y); o[6] = f2bf(x1.z); o[7] = f2bf(x1.w);
    *reinterpret_cast<short8*>(out) = o;
}

// out[ncol][k0..k0+7] = bf16(in[k][ncol]) for in [K][Nc] row-major
__device__ __forceinline__ void transpose8(const float* __restrict__ in, short* __restrict__ out,
                                           int c, int K, int Nc) {
    const int o0 = c * 8;
    const int ncol = o0 / K;
    const int k0 = o0 % K;
    short8 o;
#pragma unroll
    for (int j = 0; j < 8; ++j) o[j] = f2bf(in[(size_t)(k0 + j) * Nc + ncol]);
    *reinterpret_cast<short8*>(out + o0) = o;
}

// ---------------------------------------------------------------------------
// prep_all: bf16 copies of v1,v2 + transposed bf16 weights — one launch.
// block ranges: [0,1024) v1 | [1024,3072) v2 | [3072,3136) gene_actT
//               [3136,3168) Wrna1T | [3168,3184) Wrna2T
// ---------------------------------------------------------------------------
__global__ __launch_bounds__(256) void prep_all(const float* __restrict__ v1,
                                                const float* __restrict__ v2,
                                                const float* __restrict__ gene_act,
                                                const float* __restrict__ W1,
                                                const float* __restrict__ W2,
                                                short* __restrict__ cv1,
                                                short* __restrict__ cv2)
{
    const int b = blockIdx.x, t = threadIdx.x;
    if (b < 1024) {
        const int c = b * 256 + t;
        cvt8(v1 + (size_t)c * 8, cv1 + (size_t)c * 8);
    } else if (b < 3072) {
        const int c = (b - 1024) * 256 + t;
        cvt8(v2 + (size_t)c * 8, cv2 + (size_t)c * 8);
    } else if (b < 3136) {
        transpose8(gene_act, g_gaT, (b - 3072) * 256 + t, 512, 256);
    } else if (b < 3168) {
        transpose8(W1, g_W1T, (b - 3136) * 256 + t, 256, 256);
    } else {
        transpose8(W2, g_W2T, (b - 3168) * 256 + t, 256, 128);
    }
}

// ---------------------------------------------------------------------------
// embed_u_fused: exact fp32 e = u @ Wb, plus bf16(w_prod-folded) copy into
// bf_sel(bu_sel) and rowdot(w_add) into g_a.  One block per row, 128 threads.
// ---------------------------------------------------------------------------
__global__ __launch_bounds__(128) void embed_u_fused(const float* __restrict__ u,
                                                     const float* __restrict__ Wb,
                                                     const float* __restrict__ w_prod,
                                                     const float* __restrict__ w_add,
                                                     float* __restrict__ e,
                                                     int bu_sel, int a_ofs, int K)
{
    __shared__ float sU[128];
    __shared__ float s2[2];
    const int row = blockIdx.x;
    const int d = threadIdx.x;
    if (d < K) sU[d] = u[row * K + d];
    __syncthreads();
    float acc = 0.f;
    for (int k = 0; k < K; ++k) acc = fmaf(sU[k], Wb[k * 128 + d], acc);
    e[row * 128 + d] = acc;
    bf_sel(bu_sel)[row * 128 + d] = f2bf(acc * w_prod[d]);
    float v = acc * w_add[d];
#pragma unroll
    for (int off = 32; off > 0; off >>= 1) v += __shfl_down(v, off, 64);
    if ((d & 63) == 0) s2[d >> 6] = v;
    __syncthreads();
    if (d == 0) g_a[a_ofs + row] = s2[0] + s2[1];
}

// ---------------------------------------------------------------------------
// rowdot: g_a[ofs + row] = sum_d E[row,d] * w[d]   (fp32 E, D=128)
// ---------------------------------------------------------------------------
__global__ __launch_bounds__(128) void rowdot_kernel(const float* __restrict__ E,
                                                     const float* __restrict__ w,
                                                     int ofs)
{
    const int row = blockIdx.x;
    const int d = threadIdx.x;
    float v = E[row * 128 + d] * w[d];
#pragma unroll
    for (int off = 32; off > 0; off >>= 1) v += __shfl_down(v, off, 64);
    __shared__ float s2[2];
    if ((d & 63) == 0) s2[d >> 6] = v;
    __syncthreads();
    if (d == 0) g_a[ofs + row] = s2[0] + s2[1];
}

// ---------------------------------------------------------------------------
// mfma_nn: C[rows,Nc] = act(A @ BT^T) in bf16 MFMA, fp32 accum.
// A [rows][KTOT] bf16 (device pointer into d_out scratch),
// BT = wt_sel(bt_sel) [Nc][KTOT] bf16 (pre-transposed weight global).
// outb = bf_sel(outb_sel) if outb_sel>=0 else outb_ptr.
// 128x128 tile, 2x2 waves, 4x4 frags of 16x16x32; K chunks of 128 in LDS,
// XOR-swizzled (byte ^= (row&7)<<4).  Writes bf16 always, fp32 optional.
// ---------------------------------------------------------------------------
template<int KTOT, bool RELU, bool WF32>
__global__ __launch_bounds__(256) void mfma_nn(const short* __restrict__ A,
                                               int bt_sel, int outb_sel,
                                               short* __restrict__ outb_ptr,
                                               float* __restrict__ outf)
{
    __shared__ __align__(16) short sA[128 * 128];
    __shared__ __align__(16) short sB[128 * 128];
    const short* BT = wt_sel(bt_sel);
    short* outb = (outb_sel >= 0) ? bf_sel(outb_sel) : outb_ptr;
    const int t = threadIdx.x;
    const int l = t & 63;
    const int row0 = blockIdx.y * 128;
    const int col0 = blockIdx.x * 128;
    const int Nc = gridDim.x * 128;

    const int w  = t >> 6;
    const int wm = (w >> 1) * 64;
    const int wn = (w & 1) * 64;
    const int lr  = l & 15;
    const int lkb = (l >> 4) * 16;

    f32x4 acc[4][4] = {};
    for (int k0 = 0; k0 < KTOT; k0 += 128) {
        {
            const char* gA = (const char*)(A + (size_t)row0 * KTOT + k0);
            const char* gB = (const char*)(BT + (size_t)col0 * KTOT + k0);
            char* cA = (char*)sA;
            char* cB = (char*)sB;
#pragma unroll
            for (int c = 0; c < 8; ++c) {
                const int idx = c * 256 + t;             // 16B chunk, 0..2047
                const int row = idx >> 4;
                const int sub = idx & 15;
                const int dst = row * 256 + ((sub * 16) ^ ((row & 7) << 4));
                const size_t src = (size_t)row * (KTOT * 2) + sub * 16;
                const short8 va = *reinterpret_cast<const short8*>(gA + src);
                const short8 vb = *reinterpret_cast<const short8*>(gB + src);
                *reinterpret_cast<short8*>(cA + dst) = va;
                *reinterpret_cast<short8*>(cB + dst) = vb;
            }
        }
        __syncthreads();
        const char* cA = (const char*)sA;
        const char* cB = (const char*)sB;
#pragma unroll
        for (int kk = 0; kk < 4; ++kk) {
            const int kb = kk * 64 + lkb;
            short8 a[4], b[4];
#pragma unroll
            for (int i = 0; i < 4; ++i) {
                const int rowA = wm + i * 16 + lr;
                a[i] = *reinterpret_cast<const short8*>(cA + rowA * 256 + (kb ^ ((rowA & 7) << 4)));
                const int rowB = wn + i * 16 + lr;
                b[i] = *reinterpret_cast<const short8*>(cB + rowB * 256 + (kb ^ ((rowB & 7) << 4)));
            }
#pragma unroll
            for (int i = 0; i < 4; ++i)
#pragma unroll
                for (int j = 0; j < 4; ++j)
                    acc[i][j] = __builtin_amdgcn_mfma_f32_16x16x32_bf16(a[i], b[j], acc[i][j], 0, 0, 0);
        }
        __syncthreads();
    }

    const int r4 = (l >> 4) * 4;
#pragma unroll
    for (int i = 0; i < 4; ++i) {
#pragma unroll
        for (int r = 0; r < 4; ++r) {
            const int grow = row0 + wm + i * 16 + r4 + r;
#pragma unroll
            for (int j = 0; j < 4; ++j) {
                float x = acc[i][j][r];
                if (RELU) x = fmaxf(x, 0.f);
                const size_t oi = (size_t)grow * Nc + col0 + wn + j * 16 + lr;
                outb[oi] = f2bf(x);
                if (WF32) outf[oi] = x;
            }
        }
    }
}

// ---------------------------------------------------------------------------
// pair_mfma: out[n,m] = act( sum_d EU'[n,d]*EV[m,d] + a_u[n] + a_v[m] + bias )
// ---------------------------------------------------------------------------
template<int ACT>
__global__ __launch_bounds__(256) void pair_mfma(int which,
                                                 const float* __restrict__ bias_p,
                                                 float* __restrict__ outp,
                                                 int ofsU, int ofsV)
{
    __shared__ __align__(16) short sA[128 * 128];
    __shared__ __align__(16) short sB[128 * 128];
    const int t = threadIdx.x;
    const int l = t & 63;
    const int row0 = blockIdx.y * 128;
    const int col0 = blockIdx.x * 128;

    {
        const short8* gA = reinterpret_cast<const short8*>(bf_sel(which ? 2 : 0)) + (size_t)row0 * 16;
        const short8* gB = reinterpret_cast<const short8*>(bf_sel(which ? 3 : 1)) + (size_t)col0 * 16;
        char* cA = (char*)sA;
        char* cB = (char*)sB;
#pragma unroll
        for (int c = 0; c < 8; ++c) {
            const int idx = c * 256 + t;
            const int row = idx >> 4;
            const int sub = idx & 15;
            const int dst = row * 256 + ((sub * 16) ^ ((row & 7) << 4));
            const short8 va = gA[idx];
            const short8 vb = gB[idx];
            *reinterpret_cast<short8*>(cA + dst) = va;
            *reinterpret_cast<short8*>(cB + dst) = vb;
        }
    }
    __syncthreads();

    const int w  = t >> 6;
    const int wm = (w >> 1) * 64;
    const int wn = (w & 1) * 64;
    const int lr = l & 15;
    const int lkb = (l >> 4) * 16;

    f32x4 acc[4][4] = {};
    const char* cA = (const char*)sA;
    const char* cB = (const char*)sB;
#pragma unroll
    for (int kk = 0; kk < 4; ++kk) {
        const int kb = kk * 64 + lkb;
        short8 a[4], b[4];
#pragma unroll
        for (int i = 0; i < 4; ++i) {
            const int rowA = wm + i * 16 + lr;
            a[i] = *reinterpret_cast<const short8*>(cA + rowA * 256 + (kb ^ ((rowA & 7) << 4)));
            const int rowB = wn + i * 16 + lr;
            b[i] = *reinterpret_cast<const short8*>(cB + rowB * 256 + (kb ^ ((rowB & 7) << 4)));
        }
#pragma unroll
        for (int i = 0; i < 4; ++i)
#pragma unroll
            for (int j = 0; j < 4; ++j)
                acc[i][j] = __builtin_amdgcn_mfma_f32_16x16x32_bf16(a[i], b[j], acc[i][j], 0, 0, 0);
    }

    const float bias = *bias_p;
    const int r4 = (l >> 4) * 4;
    float au[4][4];
#pragma unroll
    for (int i = 0; i < 4; ++i)
#pragma unroll
        for (int r = 0; r < 4; ++r)
            au[i][r] = g_a[ofsU + row0 + wm + i * 16 + r4 + r];
    float av[4];
#pragma unroll
    for (int j = 0; j < 4; ++j)
        av[j] = g_a[ofsV + col0 + wn + j * 16 + lr];

#pragma unroll
    for (int i = 0; i < 4; ++i) {
#pragma unroll
        for (int r = 0; r < 4; ++r) {
            const int grow = row0 + wm + i * 16 + r4 + r;
            float* orow = outp + (size_t)grow * M_GENES + col0 + wn;
#pragma unroll
            for (int j = 0; j < 4; ++j) {
                float x = acc[i][j][r] + au[i][r] + av[j] + bias;
                if (ACT == 0) x = fmaxf(x, 0.f);
                else          x = __builtin_amdgcn_rcpf(1.f + __expf(-x));
                orow[j * 16 + lr] = x;
            }
        }
    }
}

// ---------------------------------------------------------------------------
extern "C" void kernel_launch(void* const* d_in, const int* in_sizes, int n_in,
                              void* d_out, int out_size, void* d_ws, size_t ws_size,
                              hipStream_t stream)
{
    const float* u1       = (const float*)d_in[0];   // [4096,100]
    const float* u2       = (const float*)d_in[1];   // [4096,100]
    const float* v1       = (const float*)d_in[2];   // [8192,256]
    const float* v2       = (const float*)d_in[3];   // [8192,512]
    const float* Wb1      = (const float*)d_in[4];   // [100,128]
    const float* Wb2      = (const float*)d_in[5];   // [100,128]
    const float* Wrna1    = (const float*)d_in[6];   // [256,256]
    const float* Wrna2    = (const float*)d_in[7];   // [256,128]
    const float* gene_act = (const float*)d_in[8];   // [512,256]
    const float* w_prod1  = (const float*)d_in[9];   // [128]
    const float* w_add1   = (const float*)d_in[10];  // [256]
    const float* w_prod2  = (const float*)d_in[11];  // [128]
    const float* w_add2   = (const float*)d_in[12];  // [256]
    const float* bias1    = (const float*)d_in[13];  // scalar
    const float* bias2    = (const float*)d_in[14];  // scalar

    float* out  = (float*)d_out;
    float* out1 = out;                                      // [4096,8192]
    float* out2 = out1 + (size_t)N_CELLS * M_GENES;         // [4096,8192]
    float* eu1  = out2 + (size_t)N_CELLS * M_GENES;         // [4096,128]
    float* ev1  = eu1 + N_CELLS * 128;                      // [8192,128]
    float* eu2  = ev1 + M_GENES * 128;                      // [4096,128]
    float* ev2  = eu2 + N_CELLS * 128;                      // [8192,128]

    // 20 MB of bf16 scratch inside the out2 region (128 MB): out2 is written
    // last, by pair_mfma<1>, after every scratch consumer has completed.
    short* cv1 = (short*)out2;                 // bf16(v1)  [8192][256]
    short* cv2 = cv1 + (size_t)M_GENES * 256;  // bf16(v2)  [8192][512]
    short* H0  = cv2 + (size_t)M_GENES * 512;  // hidden    [8192][256]
    short* H1  = H0  + (size_t)M_GENES * 256;  // hidden    [8192][256]

    // bf16 inputs + transposed weights (one launch)
    prep_all<<<3184, 256, 0, stream>>>(v1, v2, gene_act, Wrna1, Wrna2, cv1, cv2);

    // u embeddings: exact fp32 + bf16(w_prod-folded) + rowdot fused
    embed_u_fused<<<N_CELLS, 128, 0, stream>>>(u1, Wb1, w_prod1, w_add1, eu1, 0, 0,     100);
    embed_u_fused<<<N_CELLS, 128, 0, stream>>>(u2, Wb2, w_prod2, w_add2, eu2, 2, 12288, 100);

    // v-embedding chain in bf16 MFMA (fp32 accum)
    mfma_nn<512, false, false><<<dim3(2, 64), 256, 0, stream>>>(cv2, 0, -1, H1, nullptr); // H1 = v2@gene_act
    mfma_nn<256, true,  false><<<dim3(2, 64), 256, 0, stream>>>(cv1, 1, -1, H0, nullptr); // H0 = relu(v1@W1)
    mfma_nn<256, false, true ><<<dim3(1, 64), 256, 0, stream>>>(H0,  2,  1, nullptr, ev1); // ev1 = H0@W2
    mfma_nn<256, true,  false><<<dim3(2, 64), 256, 0, stream>>>(H1,  1, -1, H0, nullptr); // H0 = relu(H1@W1)
    mfma_nn<256, false, true ><<<dim3(1, 64), 256, 0, stream>>>(H0,  2,  3, nullptr, ev2); // ev2 = H0@W2

    // per-row additive terms for ev (eu ones fused above)
    rowdot_kernel<<<M_GENES, 128, 0, stream>>>(ev1, w_add1 + 128, 4096);
    rowdot_kernel<<<M_GENES, 128, 0, stream>>>(ev2, w_add2 + 128, 16384);

    // all-pairs scores via bf16 MFMA
    pair_mfma<0><<<dim3(64, 32), 256, 0, stream>>>(0, bias1, out1, 0,     4096);
    pair_mfma<1><<<dim3(64, 32), 256, 0, stream>>>(1, bias2, out2, 12288, 16384);
}

// Round 6
// 117.739 us; speedup vs baseline: 3.3471x; 1.1722x over previous
//
#include <hip/hip_runtime.h>
#include <math.h>

#define N_CELLS 4096
#define M_GENES 8192

typedef __attribute__((ext_vector_type(8))) short short8;
typedef __attribute__((ext_vector_type(4))) float f32x4;

// per-row additive terms: a_u1[4096], a_v1[8192], a_u2[4096], a_v2[8192]
__device__ __align__(16) float g_a[24576];

// bf16 copies feeding pair MFMA (g_bu: w_prod folded; g_bv: plain)
__device__ __align__(16) short g_bu1[N_CELLS * 128];
__device__ __align__(16) short g_bv1[M_GENES * 128];
__device__ __align__(16) short g_bu2[N_CELLS * 128];
__device__ __align__(16) short g_bv2[M_GENES * 128];

// transposed bf16 weights: BT[ncol][k]
__device__ __align__(16) short g_gaT[256 * 512];       // gene_act^T
__device__ __align__(16) short g_W1T[256 * 256];       // Wrna1^T
__device__ __align__(16) short g_W2T[128 * 256];       // Wrna2^T

// IMPORTANT (round-3/4 lesson): device globals are NEVER passed as kernel
// arguments from host code (host-side name = shadow symbol, not device
// address -> GPU memory fault/abort). Access via device-side selectors only.

__device__ __forceinline__ short* bf_sel(int s) {
    switch (s) {
        case 0:  return g_bu1;
        case 1:  return g_bv1;
        case 2:  return g_bu2;
        default: return g_bv2;
    }
}

__device__ __forceinline__ const short* wt_sel(int s) {
    switch (s) {
        case 0:  return g_gaT;
        case 1:  return g_W1T;
        default: return g_W2T;
    }
}

__device__ __forceinline__ short f2bf(float f) {  // RNE fp32 -> bf16
    unsigned u = __builtin_bit_cast(unsigned, f);
    u += 0x7FFFu + ((u >> 16) & 1u);
    return (short)(u >> 16);
}

__device__ __forceinline__ void cvt8(const float* __restrict__ in, short* __restrict__ out) {
    const float4 x0 = *reinterpret_cast<const float4*>(in);
    const float4 x1 = *reinterpret_cast<const float4*>(in + 4);
    short8 o;
    o[0] = f2bf(x0.x); o[1] = f2bf(x0.y); o[2] = f2bf(x0.z); o[3] = f2bf(x0.w);
    o[4] = f2bf(x1.x); o[5] = f2bf(x1.y); o[6] = f2bf(x1.z); o[7] = f2bf(x1.w);
    *reinterpret_cast<short8*>(out) = o;
}

// out[ncol][k0..k0+7] = bf16(in[k][ncol]) for in [K][Nc] row-major
__device__ __forceinline__ void transpose8(const float* __restrict__ in, short* __restrict__ out,
                                           int c, int K, int Nc) {
    const int o0 = c * 8;
    const int ncol = o0 / K;
    const int k0 = o0 % K;
    short8 o;
#pragma unroll
    for (int j = 0; j < 8; ++j) o[j] = f2bf(in[(size_t)(k0 + j) * Nc + ncol]);
    *reinterpret_cast<short8*>(out + o0) = o;
}

// ---------------------------------------------------------------------------
// prep_emb: ONE launch for all input prep + u embeddings.
// block ranges:
//  [0,1024)      bf16(v1)           [1024,3072) bf16(v2)
//  [3072,3136)   gene_act^T         [3136,3168) Wrna1^T    [3168,3184) Wrna2^T
//  [3184,5232)   embed u1 (2 rows/block: fp32 eu + bf16 w_prod-fold + rowdot)
//  [5232,7280)   embed u2
// ---------------------------------------------------------------------------
__global__ __launch_bounds__(256) void prep_emb(const float* __restrict__ v1,
                                                const float* __restrict__ v2,
                                                const float* __restrict__ gene_act,
                                                const float* __restrict__ W1,
                                                const float* __restrict__ W2,
                                                short* __restrict__ cv1,
                                                short* __restrict__ cv2,
                                                const float* __restrict__ u1,
                                                const float* __restrict__ u2,
                                                const float* __restrict__ Wb1,
                                                const float* __restrict__ Wb2,
                                                const float* __restrict__ w_prod1,
                                                const float* __restrict__ w_add1,
                                                const float* __restrict__ w_prod2,
                                                const float* __restrict__ w_add2,
                                                float* __restrict__ eu1,
                                                float* __restrict__ eu2)
{
    __shared__ float sU[2][128];
    __shared__ float s2[4];
    const int b = blockIdx.x, t = threadIdx.x;
    if (b < 1024) {
        const int c = b * 256 + t;
        cvt8(v1 + (size_t)c * 8, cv1 + (size_t)c * 8);
    } else if (b < 3072) {
        const int c = (b - 1024) * 256 + t;
        cvt8(v2 + (size_t)c * 8, cv2 + (size_t)c * 8);
    } else if (b < 3136) {
        transpose8(gene_act, g_gaT, (b - 3072) * 256 + t, 512, 256);
    } else if (b < 3168) {
        transpose8(W1, g_W1T, (b - 3136) * 256 + t, 256, 256);
    } else if (b < 3184) {
        transpose8(W2, g_W2T, (b - 3168) * 256 + t, 256, 128);
    } else {
        const int which = (b < 5232) ? 0 : 1;
        const int bl = b - (which ? 5232 : 3184);          // [0,2048)
        const float* u      = which ? u2 : u1;
        const float* Wb     = which ? Wb2 : Wb1;
        const float* w_prod = which ? w_prod2 : w_prod1;
        const float* w_add  = which ? w_add2 : w_add1;
        float* e            = which ? eu2 : eu1;
        short* bu           = bf_sel(which ? 2 : 0);
        const int a_ofs     = which ? 12288 : 0;
        const int half = t >> 7;                           // 0/1: row within block
        const int row = bl * 2 + half;
        const int d = t & 127;
        if (d < 100) sU[half][d] = u[row * 100 + d];
        __syncthreads();
        float acc = 0.f;
#pragma unroll
        for (int k = 0; k < 100; ++k) acc = fmaf(sU[half][k], Wb[k * 128 + d], acc);
        e[row * 128 + d] = acc;
        bu[row * 128 + d] = f2bf(acc * w_prod[d]);
        float v = acc * w_add[d];
#pragma unroll
        for (int off = 32; off > 0; off >>= 1) v += __shfl_down(v, off, 64);
        if ((t & 63) == 0) s2[t >> 6] = v;
        __syncthreads();
        if (t == 0)   g_a[a_ofs + row]     = s2[0] + s2[1];
        if (t == 128) g_a[a_ofs + row]     = s2[2] + s2[3];
    }
}

// ---------------------------------------------------------------------------
// chain2: up to two independent bf16-MFMA GEMM jobs in one launch.
// Per job: C[rows, nx*128] = act(A @ wt_sel(bt)^T); A [rows][K] bf16.
// 128x128 tile, 2x2 waves, 4x4 frags of 16x16x32, K chunks of 128 in LDS,
// XOR-swizzled (byte ^= (row&7)<<4). Optional fp32 out and fused rowdot
// (requires nx==1: block owns complete rows).
// ---------------------------------------------------------------------------
struct Job {
    const short* A;
    short* outb_ptr;        // used when outb_sel < 0
    float* outf;            // optional fp32 output
    const float* w_addv;    // non-null => fused rowdot into g_a[a_ofs+row]
    int bt_sel;
    int outb_sel;           // >=0 => bf_sel(outb_sel)
    int a_ofs;
    int K;
    int relu;
    int nx;                 // tiles in N (1 or 2)
};

__global__ __launch_bounds__(256) void chain2(Job j0, Job j1, int split)
{
    __shared__ __align__(16) short sA[128 * 128];
    __shared__ __align__(16) short sB[128 * 128];
    __shared__ float sRow[128];
    const int t = threadIdx.x;
    const int l = t & 63;
    int b = blockIdx.x;
    const Job j = (b < split) ? j0 : j1;
    if (b >= split) b -= split;
    const int bx = b & (j.nx - 1);
    const int by = (j.nx == 2) ? (b >> 1) : b;
    const int row0 = by * 128, col0 = bx * 128;
    const int K = j.K;
    const int Nc = j.nx * 128;
    const short* BT = wt_sel(j.bt_sel);
    short* outb = (j.outb_sel >= 0) ? bf_sel(j.outb_sel) : j.outb_ptr;

    const int w  = t >> 6;
    const int wm = (w >> 1) * 64;
    const int wn = (w & 1) * 64;
    const int lr  = l & 15;
    const int lkb = (l >> 4) * 16;

    f32x4 acc[4][4] = {};
    for (int k0 = 0; k0 < K; k0 += 128) {
        {
            const char* gA = (const char*)(j.A + (size_t)row0 * K + k0);
            const char* gB = (const char*)(BT + (size_t)col0 * K + k0);
            char* cA = (char*)sA;
            char* cB = (char*)sB;
#pragma unroll
            for (int c = 0; c < 8; ++c) {
                const int idx = c * 256 + t;             // 16B chunk, 0..2047
                const int row = idx >> 4;
                const int sub = idx & 15;
                const int dst = row * 256 + ((sub * 16) ^ ((row & 7) << 4));
                const size_t src = (size_t)row * (2 * K) + sub * 16;
                const short8 va = *reinterpret_cast<const short8*>(gA + src);
                const short8 vb = *reinterpret_cast<const short8*>(gB + src);
                *reinterpret_cast<short8*>(cA + dst) = va;
                *reinterpret_cast<short8*>(cB + dst) = vb;
            }
        }
        __syncthreads();
        const char* cA = (const char*)sA;
        const char* cB = (const char*)sB;
#pragma unroll
        for (int kk = 0; kk < 4; ++kk) {
            const int kb = kk * 64 + lkb;
            short8 a[4], bfr[4];
#pragma unroll
            for (int i = 0; i < 4; ++i) {
                const int rowA = wm + i * 16 + lr;
                a[i] = *reinterpret_cast<const short8*>(cA + rowA * 256 + (kb ^ ((rowA & 7) << 4)));
                const int rowB = wn + i * 16 + lr;
                bfr[i] = *reinterpret_cast<const short8*>(cB + rowB * 256 + (kb ^ ((rowB & 7) << 4)));
            }
#pragma unroll
            for (int i = 0; i < 4; ++i)
#pragma unroll
                for (int jj = 0; jj < 4; ++jj)
                    acc[i][jj] = __builtin_amdgcn_mfma_f32_16x16x32_bf16(a[i], bfr[jj], acc[i][jj], 0, 0, 0);
        }
        __syncthreads();
    }

    const int r4 = (l >> 4) * 4;
    const bool rd = (j.w_addv != nullptr);
    float wv[4];
    float part[4][4];
    if (rd) {
#pragma unroll
        for (int jj = 0; jj < 4; ++jj) wv[jj] = j.w_addv[wn + jj * 16 + lr];
#pragma unroll
        for (int i = 0; i < 4; ++i)
#pragma unroll
            for (int r = 0; r < 4; ++r) part[i][r] = 0.f;
    }
#pragma unroll
    for (int i = 0; i < 4; ++i) {
#pragma unroll
        for (int r = 0; r < 4; ++r) {
            const int grow = row0 + wm + i * 16 + r4 + r;
#pragma unroll
            for (int jj = 0; jj < 4; ++jj) {
                float x = acc[i][jj][r];
                if (j.relu) x = fmaxf(x, 0.f);
                const size_t oi = (size_t)grow * Nc + col0 + wn + jj * 16 + lr;
                outb[oi] = f2bf(x);
                if (j.outf) j.outf[oi] = x;
                if (rd) part[i][r] = fmaf(x, wv[jj], part[i][r]);
            }
        }
    }
    if (rd) {
        // sum over the 16 lanes of each lr-group (covers this wave's 64 cols)
#pragma unroll
        for (int off = 1; off < 16; off <<= 1)
#pragma unroll
            for (int i = 0; i < 4; ++i)
#pragma unroll
                for (int r = 0; r < 4; ++r)
                    part[i][r] += __shfl_xor(part[i][r], off, 64);
        if (t < 128) sRow[t] = 0.f;
        __syncthreads();
        if ((l & 15) == 0) {
#pragma unroll
            for (int i = 0; i < 4; ++i)
#pragma unroll
                for (int r = 0; r < 4; ++r)
                    atomicAdd(&sRow[wm + i * 16 + r4 + r], part[i][r]);
        }
        __syncthreads();
        if (t < 128) g_a[j.a_ofs + row0 + t] = sRow[t];
    }
}

// ---------------------------------------------------------------------------
// pair_both: both all-pairs score matrices in one launch (blockIdx.z selects).
// out[n,m] = act( sum_d EU'[n,d]*EV[m,d] + a_u[n] + a_v[m] + bias )
// z=0: relu -> out1;  z=1: sigmoid -> out2.
// ---------------------------------------------------------------------------
__global__ __launch_bounds__(256) void pair_both(const float* __restrict__ bias1,
                                                 const float* __restrict__ bias2,
                                                 float* __restrict__ out1,
                                                 float* __restrict__ out2)
{
    __shared__ __align__(16) short sA[128 * 128];
    __shared__ __align__(16) short sB[128 * 128];
    const int which = blockIdx.z;
    const int t = threadIdx.x;
    const int l = t & 63;
    const int row0 = blockIdx.y * 128;
    const int col0 = blockIdx.x * 128;

    {
        const short8* gA = reinterpret_cast<const short8*>(bf_sel(which ? 2 : 0)) + (size_t)row0 * 16;
        const short8* gB = reinterpret_cast<const short8*>(bf_sel(which ? 3 : 1)) + (size_t)col0 * 16;
        char* cA = (char*)sA;
        char* cB = (char*)sB;
#pragma unroll
        for (int c = 0; c < 8; ++c) {
            const int idx = c * 256 + t;
            const int row = idx >> 4;
            const int sub = idx & 15;
            const int dst = row * 256 + ((sub * 16) ^ ((row & 7) << 4));
            const short8 va = gA[idx];
            const short8 vb = gB[idx];
            *reinterpret_cast<short8*>(cA + dst) = va;
            *reinterpret_cast<short8*>(cB + dst) = vb;
        }
    }
    __syncthreads();

    const int w  = t >> 6;
    const int wm = (w >> 1) * 64;
    const int wn = (w & 1) * 64;
    const int lr = l & 15;
    const int lkb = (l >> 4) * 16;

    f32x4 acc[4][4] = {};
    const char* cA = (const char*)sA;
    const char* cB = (const char*)sB;
#pragma unroll
    for (int kk = 0; kk < 4; ++kk) {
        const int kb = kk * 64 + lkb;
        short8 a[4], bfr[4];
#pragma unroll
        for (int i = 0; i < 4; ++i) {
            const int rowA = wm + i * 16 + lr;
            a[i] = *reinterpret_cast<const short8*>(cA + rowA * 256 + (kb ^ ((rowA & 7) << 4)));
            const int rowB = wn + i * 16 + lr;
            bfr[i] = *reinterpret_cast<const short8*>(cB + rowB * 256 + (kb ^ ((rowB & 7) << 4)));
        }
#pragma unroll
        for (int i = 0; i < 4; ++i)
#pragma unroll
            for (int jj = 0; jj < 4; ++jj)
                acc[i][jj] = __builtin_amdgcn_mfma_f32_16x16x32_bf16(a[i], bfr[jj], acc[i][jj], 0, 0, 0);
    }

    const float bias = which ? *bias2 : *bias1;
    float* outp = which ? out2 : out1;
    const int ofsU = which ? 12288 : 0;
    const int ofsV = which ? 16384 : 4096;
    const int r4 = (l >> 4) * 4;
    float au[4][4];
#pragma unroll
    for (int i = 0; i < 4; ++i)
#pragma unroll
        for (int r = 0; r < 4; ++r)
            au[i][r] = g_a[ofsU + row0 + wm + i * 16 + r4 + r];
    float av[4];
#pragma unroll
    for (int jj = 0; jj < 4; ++jj)
        av[jj] = g_a[ofsV + col0 + wn + jj * 16 + lr];

#pragma unroll
    for (int i = 0; i < 4; ++i) {
#pragma unroll
        for (int r = 0; r < 4; ++r) {
            const int grow = row0 + wm + i * 16 + r4 + r;
            float* orow = outp + (size_t)grow * M_GENES + col0 + wn;
#pragma unroll
            for (int jj = 0; jj < 4; ++jj) {
                float x = acc[i][jj][r] + au[i][r] + av[jj] + bias;
                if (which == 0) x = fmaxf(x, 0.f);
                else            x = __builtin_amdgcn_rcpf(1.f + __expf(-x));
                orow[jj * 16 + lr] = x;
            }
        }
    }
}

// ---------------------------------------------------------------------------
extern "C" void kernel_launch(void* const* d_in, const int* in_sizes, int n_in,
                              void* d_out, int out_size, void* d_ws, size_t ws_size,
                              hipStream_t stream)
{
    const float* u1       = (const float*)d_in[0];   // [4096,100]
    const float* u2       = (const float*)d_in[1];   // [4096,100]
    const float* v1       = (const float*)d_in[2];   // [8192,256]
    const float* v2       = (const float*)d_in[3];   // [8192,512]
    const float* Wb1      = (const float*)d_in[4];   // [100,128]
    const float* Wb2      = (const float*)d_in[5];   // [100,128]
    const float* Wrna1    = (const float*)d_in[6];   // [256,256]
    const float* Wrna2    = (const float*)d_in[7];   // [256,128]
    const float* gene_act = (const float*)d_in[8];   // [512,256]
    const float* w_prod1  = (const float*)d_in[9];   // [128]
    const float* w_add1   = (const float*)d_in[10];  // [256]
    const float* w_prod2  = (const float*)d_in[11];  // [128]
    const float* w_add2   = (const float*)d_in[12];  // [256]
    const float* bias1    = (const float*)d_in[13];  // scalar
    const float* bias2    = (const float*)d_in[14];  // scalar

    float* out  = (float*)d_out;
    float* out1 = out;                                      // [4096,8192]
    float* out2 = out1 + (size_t)N_CELLS * M_GENES;         // [4096,8192]
    float* eu1  = out2 + (size_t)N_CELLS * M_GENES;         // [4096,128]
    float* ev1  = eu1 + N_CELLS * 128;                      // [8192,128]
    float* eu2  = ev1 + M_GENES * 128;                      // [4096,128]
    float* ev2  = eu2 + N_CELLS * 128;                      // [8192,128]

    // 24 MB of bf16 scratch inside the out2 region (128 MB): out2 is written
    // last (pair_both z=1), after every scratch consumer has completed.
    short* cv1 = (short*)out2;                 // bf16(v1)  [8192][256]
    short* cv2 = cv1 + (size_t)M_GENES * 256;  // bf16(v2)  [8192][512]
    short* H0  = cv2 + (size_t)M_GENES * 512;  // hidden    [8192][256]
    short* H1  = H0  + (size_t)M_GENES * 256;  // hidden    [8192][256]
    short* H0b = H1  + (size_t)M_GENES * 256;  // hidden    [8192][256]

    // L1: all prep + u embeddings (one launch)
    prep_emb<<<7280, 256, 0, stream>>>(v1, v2, gene_act, Wrna1, Wrna2, cv1, cv2,
                                       u1, u2, Wb1, Wb2, w_prod1, w_add1,
                                       w_prod2, w_add2, eu1, eu2);

    // L2: H1 = v2@gaT (K=512)  ||  H0 = relu(v1@W1T)
    Job jH1 = { cv2, H1, nullptr, nullptr, 0, -1, 0,     512, 0, 2 };
    Job jH0 = { cv1, H0, nullptr, nullptr, 1, -1, 0,     256, 1, 2 };
    chain2<<<256, 256, 0, stream>>>(jH1, jH0, 128);

    // L3: ev1 = H0@W2T (+rowdot, +bf16->g_bv1)  ||  H0b = relu(H1@W1T)
    Job jev1 = { H0, nullptr, ev1, w_add1 + 128, 2, 1, 4096,  256, 0, 1 };
    Job jH0b = { H1, H0b, nullptr, nullptr,      1, -1, 0,    256, 1, 2 };
    chain2<<<192, 256, 0, stream>>>(jev1, jH0b, 64);

    // L4: ev2 = H0b@W2T (+rowdot, +bf16->g_bv2)
    Job jev2 = { H0b, nullptr, ev2, w_add2 + 128, 2, 3, 16384, 256, 0, 1 };
    chain2<<<64, 256, 0, stream>>>(jev2, jev2, 64);

    // L5: both all-pairs score matrices
    pair_both<<<dim3(64, 32, 2), 256, 0, stream>>>(bias1, bias2, out1, out2);
}

// Round 7
// 112.130 us; speedup vs baseline: 3.5145x; 1.0500x over previous
//
#include <hip/hip_runtime.h>
#include <math.h>

#define N_CELLS 4096
#define M_GENES 8192

typedef __attribute__((ext_vector_type(8))) short short8;
typedef __attribute__((ext_vector_type(4))) float f32x4;

// per-row additive terms: a_u1[4096], a_v1[8192], a_u2[4096], a_v2[8192]
__device__ __align__(16) float g_a[24576];

// bf16 copies feeding pair MFMA (g_bu: w_prod folded; g_bv: plain)
__device__ __align__(16) short g_bu1[N_CELLS * 128];
__device__ __align__(16) short g_bv1[M_GENES * 128];
__device__ __align__(16) short g_bu2[N_CELLS * 128];
__device__ __align__(16) short g_bv2[M_GENES * 128];

// transposed bf16 weights: BT[ncol][k]
__device__ __align__(16) short g_gaT[256 * 512];       // gene_act^T
__device__ __align__(16) short g_W1T[256 * 256];       // Wrna1^T
__device__ __align__(16) short g_W2T[128 * 256];       // Wrna2^T

// IMPORTANT (round-3/4 lesson): device globals are NEVER passed as kernel
// arguments from host code (host-side name = shadow symbol, not device
// address -> GPU memory fault/abort). Access via device-side selectors only.

__device__ __forceinline__ short* bf_sel(int s) {
    switch (s) {
        case 0:  return g_bu1;
        case 1:  return g_bv1;
        case 2:  return g_bu2;
        default: return g_bv2;
    }
}

__device__ __forceinline__ const short* wt_sel(int s) {
    switch (s) {
        case 0:  return g_gaT;
        case 1:  return g_W1T;
        default: return g_W2T;
    }
}

__device__ __forceinline__ short f2bf(float f) {  // RNE fp32 -> bf16
    unsigned u = __builtin_bit_cast(unsigned, f);
    u += 0x7FFFu + ((u >> 16) & 1u);
    return (short)(u >> 16);
}

__device__ __forceinline__ void cvt8(const float* __restrict__ in, short* __restrict__ out) {
    const float4 x0 = *reinterpret_cast<const float4*>(in);
    const float4 x1 = *reinterpret_cast<const float4*>(in + 4);
    short8 o;
    o[0] = f2bf(x0.x); o[1] = f2bf(x0.y); o[2] = f2bf(x0.z); o[3] = f2bf(x0.w);
    o[4] = f2bf(x1.x); o[5] = f2bf(x1.y); o[6] = f2bf(x1.z); o[7] = f2bf(x1.w);
    *reinterpret_cast<short8*>(out) = o;
}

// out[ncol][k0..k0+7] = bf16(in[k][ncol]) for in [K][Nc] row-major
__device__ __forceinline__ void transpose8(const float* __restrict__ in, short* __restrict__ out,
                                           int c, int K, int Nc) {
    const int o0 = c * 8;
    const int ncol = o0 / K;
    const int k0 = o0 % K;
    short8 o;
#pragma unroll
    for (int j = 0; j < 8; ++j) o[j] = f2bf(in[(size_t)(k0 + j) * Nc + ncol]);
    *reinterpret_cast<short8*>(out + o0) = o;
}

// ---------------------------------------------------------------------------
// Chain GEMM job: C[rows, nx*128] = act(A @ wt_sel(bt)^T)
// A is bf16 [rows][K] (A) or fp32 [rows][K] (Af, cvt during LDS staging).
// 64x128 tile, 4 waves (2 row x 2 col), acc[2][4] frags of 16x16x32.
// LDS XOR-swizzled (byte ^= (row&7)<<4). Optional fp32 out and fused rowdot.
// ---------------------------------------------------------------------------
struct Job {
    const short* A;         // bf16 A (used when Af == nullptr)
    const float* Af;        // fp32 A (staged with on-the-fly f2bf)
    short* outb_ptr;        // used when outb_sel < 0
    float* outf;            // optional fp32 output
    const float* w_addv;    // non-null => fused rowdot into g_a[a_ofs+row] (nx==1)
    int bt_sel;
    int outb_sel;           // >=0 => bf_sel(outb_sel)
    int a_ofs;
    int K;
    int relu;
    int nx;                 // tiles in N (1 or 2)
};

__device__ __forceinline__ void chain_block(const Job& j, int b,
                                            short* sAs, short* sBs, float* sRow)
{
    const int t = threadIdx.x, l = t & 63;
    const int bx = (j.nx == 2) ? (b & 1) : 0;
    const int by = (j.nx == 2) ? (b >> 1) : b;
    const int row0 = by * 64, col0 = bx * 128;
    const int K = j.K, Nc = j.nx * 128;
    const short* BT = wt_sel(j.bt_sel);
    short* outb = (j.outb_sel >= 0) ? bf_sel(j.outb_sel) : j.outb_ptr;
    const int w = t >> 6, wm = (w >> 1) * 32, wn = (w & 1) * 64;
    const int lr = l & 15, lkb = (l >> 4) * 16;
    char* cA = (char*)sAs;
    char* cB = (char*)sBs;

    f32x4 acc[2][4] = {};
    for (int k0 = 0; k0 < K; k0 += 128) {
        if (j.Af) {                                   // fp32 A: cvt while staging
            const float* gAf = j.Af + (size_t)row0 * K + k0;
#pragma unroll
            for (int c = 0; c < 4; ++c) {
                const int idx = c * 256 + t;          // 16B chunk, 0..1023
                const int row = idx >> 4, sub = idx & 15;
                const int dst = row * 256 + ((sub * 16) ^ ((row & 7) << 4));
                cvt8(gAf + (size_t)row * K + sub * 8, (short*)(cA + dst));
            }
        } else {
            const char* gA = (const char*)(j.A + (size_t)row0 * K + k0);
#pragma unroll
            for (int c = 0; c < 4; ++c) {
                const int idx = c * 256 + t;
                const int row = idx >> 4, sub = idx & 15;
                const int dst = row * 256 + ((sub * 16) ^ ((row & 7) << 4));
                *(short8*)(cA + dst) = *(const short8*)(gA + (size_t)row * (2 * K) + sub * 16);
            }
        }
        {
            const char* gB = (const char*)(BT + (size_t)col0 * K + k0);
#pragma unroll
            for (int c = 0; c < 8; ++c) {
                const int idx = c * 256 + t;          // 16B chunk, 0..2047
                const int row = idx >> 4, sub = idx & 15;
                const int dst = row * 256 + ((sub * 16) ^ ((row & 7) << 4));
                *(short8*)(cB + dst) = *(const short8*)(gB + (size_t)row * (2 * K) + sub * 16);
            }
        }
        __syncthreads();
#pragma unroll
        for (int kk = 0; kk < 4; ++kk) {
            const int kb = kk * 64 + lkb;
            short8 a[2], bfr[4];
#pragma unroll
            for (int i = 0; i < 2; ++i) {
                const int rowA = wm + i * 16 + lr;
                a[i] = *(const short8*)(cA + rowA * 256 + (kb ^ ((rowA & 7) << 4)));
            }
#pragma unroll
            for (int jj = 0; jj < 4; ++jj) {
                const int rowB = wn + jj * 16 + lr;
                bfr[jj] = *(const short8*)(cB + rowB * 256 + (kb ^ ((rowB & 7) << 4)));
            }
#pragma unroll
            for (int i = 0; i < 2; ++i)
#pragma unroll
                for (int jj = 0; jj < 4; ++jj)
                    acc[i][jj] = __builtin_amdgcn_mfma_f32_16x16x32_bf16(a[i], bfr[jj], acc[i][jj], 0, 0, 0);
        }
        __syncthreads();
    }

    const int r4 = (l >> 4) * 4;
    const bool rd = (j.w_addv != nullptr);
    float wv[4], part[2][4];
    if (rd) {
#pragma unroll
        for (int jj = 0; jj < 4; ++jj) wv[jj] = j.w_addv[wn + jj * 16 + lr];
#pragma unroll
        for (int i = 0; i < 2; ++i)
#pragma unroll
            for (int r = 0; r < 4; ++r) part[i][r] = 0.f;
    }
#pragma unroll
    for (int i = 0; i < 2; ++i) {
#pragma unroll
        for (int r = 0; r < 4; ++r) {
            const int grow = row0 + wm + i * 16 + r4 + r;
#pragma unroll
            for (int jj = 0; jj < 4; ++jj) {
                float x = acc[i][jj][r];
                if (j.relu) x = fmaxf(x, 0.f);
                const size_t oi = (size_t)grow * Nc + col0 + wn + jj * 16 + lr;
                outb[oi] = f2bf(x);
                if (j.outf) j.outf[oi] = x;
                if (rd) part[i][r] = fmaf(x, wv[jj], part[i][r]);
            }
        }
    }
    if (rd) {
#pragma unroll
        for (int off = 1; off < 16; off <<= 1)
#pragma unroll
            for (int i = 0; i < 2; ++i)
#pragma unroll
                for (int r = 0; r < 4; ++r)
                    part[i][r] += __shfl_xor(part[i][r], off, 64);
        if (t < 64) sRow[t] = 0.f;
        __syncthreads();
        if ((l & 15) == 0) {
#pragma unroll
            for (int i = 0; i < 2; ++i)
#pragma unroll
                for (int r = 0; r < 4; ++r)
                    atomicAdd(&sRow[wm + i * 16 + r4 + r], part[i][r]);
        }
        __syncthreads();
        if (t < 64) g_a[j.a_ofs + row0 + t] = sRow[t];
    }
}

// ---------------------------------------------------------------------------
// pair_block: out[n,m] = act( sum_d EU'[n,d]*EV[m,d] + a_u[n] + a_v[m] + bias )
// 128x128 tile, K=128 single shot. which=0: relu->out1, which=1: sigmoid->out2.
// ---------------------------------------------------------------------------
__device__ __forceinline__ void pair_block(int which, int bb, short* sAs, short* sBs,
                                           const float* bias1, const float* bias2,
                                           float* out1, float* out2)
{
    const int t = threadIdx.x, l = t & 63;
    const int col0 = (bb & 63) * 128;
    const int row0 = (bb >> 6) * 128;
    char* cA = (char*)sAs;
    char* cB = (char*)sBs;
    {
        const short8* gA = reinterpret_cast<const short8*>(bf_sel(which ? 2 : 0)) + (size_t)row0 * 16;
        const short8* gB = reinterpret_cast<const short8*>(bf_sel(which ? 3 : 1)) + (size_t)col0 * 16;
#pragma unroll
        for (int c = 0; c < 8; ++c) {
            const int idx = c * 256 + t;
            const int row = idx >> 4, sub = idx & 15;
            const int dst = row * 256 + ((sub * 16) ^ ((row & 7) << 4));
            const short8 va = gA[idx];
            const short8 vb = gB[idx];
            *(short8*)(cA + dst) = va;
            *(short8*)(cB + dst) = vb;
        }
    }
    __syncthreads();

    const int w  = t >> 6;
    const int wm = (w >> 1) * 64;
    const int wn = (w & 1) * 64;
    const int lr = l & 15;
    const int lkb = (l >> 4) * 16;

    f32x4 acc[4][4] = {};
#pragma unroll
    for (int kk = 0; kk < 4; ++kk) {
        const int kb = kk * 64 + lkb;
        short8 a[4], bfr[4];
#pragma unroll
        for (int i = 0; i < 4; ++i) {
            const int rowA = wm + i * 16 + lr;
            a[i] = *(const short8*)(cA + rowA * 256 + (kb ^ ((rowA & 7) << 4)));
            const int rowB = wn + i * 16 + lr;
            bfr[i] = *(const short8*)(cB + rowB * 256 + (kb ^ ((rowB & 7) << 4)));
        }
#pragma unroll
        for (int i = 0; i < 4; ++i)
#pragma unroll
            for (int jj = 0; jj < 4; ++jj)
                acc[i][jj] = __builtin_amdgcn_mfma_f32_16x16x32_bf16(a[i], bfr[jj], acc[i][jj], 0, 0, 0);
    }

    const float bias = which ? *bias2 : *bias1;
    float* outp = which ? out2 : out1;
    const int ofsU = which ? 12288 : 0;
    const int ofsV = which ? 16384 : 4096;
    const int r4 = (l >> 4) * 4;
    float au[4][4];
#pragma unroll
    for (int i = 0; i < 4; ++i)
#pragma unroll
        for (int r = 0; r < 4; ++r)
            au[i][r] = g_a[ofsU + row0 + wm + i * 16 + r4 + r];
    float av[4];
#pragma unroll
    for (int jj = 0; jj < 4; ++jj)
        av[jj] = g_a[ofsV + col0 + wn + jj * 16 + lr];

#pragma unroll
    for (int i = 0; i < 4; ++i) {
#pragma unroll
        for (int r = 0; r < 4; ++r) {
            const int grow = row0 + wm + i * 16 + r4 + r;
            float* orow = outp + (size_t)grow * M_GENES + col0 + wn;
#pragma unroll
            for (int jj = 0; jj < 4; ++jj) {
                float x = acc[i][jj][r] + au[i][r] + av[jj] + bias;
                if (which == 0) x = fmaxf(x, 0.f);
                else            x = __builtin_amdgcn_rcpf(1.f + __expf(-x));
                orow[jj * 16 + lr] = x;
            }
        }
    }
}

// ---------------------------------------------------------------------------
// embed_block: 2 u-rows per block: exact fp32 eu, bf16(w_prod-folded) copy,
// rowdot(w_add) into g_a.  b in [0,4096): b<2048 -> stream1, else stream2.
// ---------------------------------------------------------------------------
__device__ __forceinline__ void embed_block(int b,
        const float* u1, const float* u2, const float* Wb1, const float* Wb2,
        const float* wp1, const float* wa1, const float* wp2, const float* wa2,
        float* eu1, float* eu2, float* sF)
{
    float* sU = sF;          // [2][128]
    float* s2 = sF + 256;    // [4]
    const int t = threadIdx.x;
    const int which = (b >= 2048) ? 1 : 0;
    const int bl = which ? (b - 2048) : b;
    const float* u      = which ? u2 : u1;
    const float* Wb     = which ? Wb2 : Wb1;
    const float* w_prod = which ? wp2 : wp1;
    const float* w_add  = which ? wa2 : wa1;
    float* e            = which ? eu2 : eu1;
    short* bu           = bf_sel(which ? 2 : 0);
    const int a_ofs     = which ? 12288 : 0;
    const int half = t >> 7;
    const int row = bl * 2 + half;
    const int d = t & 127;
    if (d < 100) sU[half * 128 + d] = u[row * 100 + d];
    __syncthreads();
    float acc = 0.f;
#pragma unroll
    for (int k = 0; k < 100; ++k) acc = fmaf(sU[half * 128 + k], Wb[k * 128 + d], acc);
    e[row * 128 + d] = acc;
    bu[row * 128 + d] = f2bf(acc * w_prod[d]);
    float v = acc * w_add[d];
#pragma unroll
    for (int off = 32; off > 0; off >>= 1) v += __shfl_down(v, off, 64);
    if ((t & 63) == 0) s2[t >> 6] = v;
    __syncthreads();
    if (t == 0)   g_a[a_ofs + row] = s2[0] + s2[1];
    if (t == 128) g_a[a_ofs + row] = s2[2] + s2[3];
}

// ---------------------------------------------------------------------------
// kernels
// ---------------------------------------------------------------------------
__global__ __launch_bounds__(256) void prep_w(const float* __restrict__ gene_act,
                                              const float* __restrict__ W1,
                                              const float* __restrict__ W2)
{
    const int b = blockIdx.x, t = threadIdx.x;
    if (b < 64)      transpose8(gene_act, g_gaT, b * 256 + t, 512, 256);
    else if (b < 96) transpose8(W1, g_W1T, (b - 64) * 256 + t, 256, 256);
    else             transpose8(W2, g_W2T, (b - 96) * 256 + t, 256, 128);
}

// chain jobs (blocks [0,nchain)) + optional embed backfill (blocks >= nchain)
__global__ __launch_bounds__(256) void chain_embed(Job j0, Job j1, int split, int nchain,
        const float* u1, const float* u2, const float* Wb1, const float* Wb2,
        const float* wp1, const float* wa1, const float* wp2, const float* wa2,
        float* eu1, float* eu2)
{
    __shared__ __align__(16) short sMem[24576];   // 48 KB: sA 16K + sB 32K
    __shared__ float sF[264];
    const int b = blockIdx.x;
    if (b < nchain) {
        if (b < split) chain_block(j0, b, sMem, sMem + 8192, sF);
        else           chain_block(j1, b - split, sMem, sMem + 8192, sF);
    } else {
        embed_block(b - nchain, u1, u2, Wb1, Wb2, wp1, wa1, wp2, wa2, eu1, eu2, sF);
    }
}

// chain job (blocks [0,nchain)) + pair tiles (blocks >= nchain)
__global__ __launch_bounds__(256) void pair_chain(Job j, int nchain, int which,
        const float* bias1, const float* bias2, float* out1, float* out2)
{
    __shared__ __align__(16) short sMem[32768];   // 64 KB for pair
    __shared__ float sF[264];
    const int b = blockIdx.x;
    if (b < nchain) chain_block(j, b, sMem, sMem + 8192, sF);
    else            pair_block(which, b - nchain, sMem, sMem + 16384, bias1, bias2, out1, out2);
}

// ---------------------------------------------------------------------------
extern "C" void kernel_launch(void* const* d_in, const int* in_sizes, int n_in,
                              void* d_out, int out_size, void* d_ws, size_t ws_size,
                              hipStream_t stream)
{
    const float* u1       = (const float*)d_in[0];   // [4096,100]
    const float* u2       = (const float*)d_in[1];   // [4096,100]
    const float* v1       = (const float*)d_in[2];   // [8192,256]
    const float* v2       = (const float*)d_in[3];   // [8192,512]
    const float* Wb1      = (const float*)d_in[4];   // [100,128]
    const float* Wb2      = (const float*)d_in[5];   // [100,128]
    const float* Wrna1    = (const float*)d_in[6];   // [256,256]
    const float* Wrna2    = (const float*)d_in[7];   // [256,128]
    const float* gene_act = (const float*)d_in[8];   // [512,256]
    const float* w_prod1  = (const float*)d_in[9];   // [128]
    const float* w_add1   = (const float*)d_in[10];  // [256]
    const float* w_prod2  = (const float*)d_in[11];  // [128]
    const float* w_add2   = (const float*)d_in[12];  // [256]
    const float* bias1    = (const float*)d_in[13];  // scalar
    const float* bias2    = (const float*)d_in[14];  // scalar

    float* out  = (float*)d_out;
    float* out1 = out;                                      // [4096,8192]
    float* out2 = out1 + (size_t)N_CELLS * M_GENES;         // [4096,8192]
    float* eu1  = out2 + (size_t)N_CELLS * M_GENES;         // [4096,128]
    float* ev1  = eu1 + N_CELLS * 128;                      // [8192,128]
    float* eu2  = ev1 + M_GENES * 128;                      // [4096,128]
    float* ev2  = eu2 + N_CELLS * 128;                      // [8192,128]

    // 12 MB bf16 hidden scratch inside out2 (out2 written last, by pair which=1)
    short* H0  = (short*)out2;                 // [8192][256]
    short* H1  = H0 + (size_t)M_GENES * 256;   // [8192][256]
    short* H0b = H1 + (size_t)M_GENES * 256;   // [8192][256]

    // P1: transposed bf16 weights
    prep_w<<<112, 256, 0, stream>>>(gene_act, Wrna1, Wrna2);

    // P2: H1 = v2@gaT (fp32-A, K=512) || H0 = relu(v1@W1T) (fp32-A, K=256),
    //     + 4096 embed blocks backfilled
    Job jH1 = { nullptr, v2, H1, nullptr, nullptr, 0, -1, 0,     512, 0, 2 };
    Job jH0 = { nullptr, v1, H0, nullptr, nullptr, 1, -1, 0,     256, 1, 2 };
    chain_embed<<<4608, 256, 0, stream>>>(jH1, jH0, 256, 512,
        u1, u2, Wb1, Wb2, w_prod1, w_add1, w_prod2, w_add2, eu1, eu2);

    // P3: ev1 = H0@W2T (+rowdot,+bf16->g_bv1) || H0b = relu(H1@W1T)
    Job jev1 = { H0, nullptr, nullptr, ev1, w_add1 + 128, 2, 1, 4096,  256, 0, 1 };
    Job jH0b = { H1, nullptr, H0b, nullptr, nullptr,      1, -1, 0,    256, 1, 2 };
    chain_embed<<<384, 256, 0, stream>>>(jev1, jH0b, 128, 384,
        u1, u2, Wb1, Wb2, w_prod1, w_add1, w_prod2, w_add2, eu1, eu2);

    // P4: ev2 = H0b@W2T (+rowdot,+bf16->g_bv2) hidden under pair(0) -> out1
    Job jev2 = { H0b, nullptr, nullptr, ev2, w_add2 + 128, 2, 3, 16384, 256, 0, 1 };
    pair_chain<<<2176, 256, 0, stream>>>(jev2, 128, 0, bias1, bias2, out1, out2);

    // P5: pair(1) -> out2
    Job jnull = {};
    pair_chain<<<2048, 256, 0, stream>>>(jnull, 0, 1, bias1, bias2, out1, out2);
}